// Round 5
// baseline (402.873 us; speedup 1.0000x reference)
//
#include <hip/hip_runtime.h>
#include <math.h>

// Gaussian NLL + analytic grad + Hessian wrt (mu, pre-softplus-std).
// Streaming: 100.7 MB in, 234.9 MB out = 335.5 MB @ N=2^23; floor ~53 us
// @ 6.3 TB/s.
//
// R4 decomposition (double-launch): kernel k = 379.6-306.4 = 73 us
// (4.6 TB/s), fixed harness cost = 233 us. Remaining claim ~20 us.
//
// R5 theory: MLP-limited. Old shape = 8 serialized grid-stride iterations
// x 2 loads each. New shape: one-shot grid, 4 pairs/thread, ALL 8 loads
// issued before compute (96 B/lane in flight, 4x MLP). Pair indices
// spread by total-thread stride so every instruction is lane-contiguous.
// DOUBLE LAUNCH KEPT (diagnostic amplification): predict dur ~340-350 if
// theory right, ~380 if null. Final round reverts to single launch.

typedef float v2f __attribute__((ext_vector_type(2)));
typedef float v4f __attribute__((ext_vector_type(4)));

#define PAIRS_PER_THREAD 4

__device__ __forceinline__ void nll_elem(float mu, float s, float y,
                                         float& L, float& g0, float& g1,
                                         float& h00, float& h01, float& h11)
{
    // stable softplus: max(s,0) + log1p(exp(-|s|))
    float e    = __expf(-fabsf(s));
    float rec  = 1.0f / (1.0f + e);           // sigmoid(|s|)
    float sig  = (s >= 0.0f) ? rec : e * rec; // sigmoid(s), reuses e
    float stdv = fmaxf(s, 0.0f) + __logf(1.0f + e);
    float inv  = 1.0f / stdv;
    float z    = (y - mu) * inv;
    float z2   = z * z;

    L  = 0.5f * z2 + __logf(stdv) + 0.91893853320467274178f; // +0.5*log(2*pi)
    g0 = -z * inv;
    g1 = sig * (1.0f - z2) * inv;

    float inv2 = inv * inv;
    h00 = inv2;
    h01 = 2.0f * z * sig * inv2;
    h11 = sig * (1.0f - sig) * (1.0f - z2) * inv
        + sig * sig * (3.0f * z2 - 1.0f) * inv2;
}

__global__ __launch_bounds__(256) void unll_kernel(
    const v4f* __restrict__ yp2,   // [NP] of (mu0,s0,mu1,s1)
    const v2f* __restrict__ yt2,   // [NP] of (y0,y1)
    v2f* __restrict__ loss2,       // [NP]
    v4f* __restrict__ g2,          // [NP] of (g00,g01,g10,g11)
    v4f* __restrict__ h1,          // [2*NP] of (h00,h01,h10,h11)
    int npairs)
{
    const int gtid = blockIdx.x * blockDim.x + threadIdx.x;
    const int T    = gridDim.x * blockDim.x;   // pair stride between slots

    // Phase 1: issue ALL loads back-to-back (max MLP).
    v4f P[PAIRS_PER_THREAD];
    v2f Y[PAIRS_PER_THREAD];
#pragma unroll
    for (int j = 0; j < PAIRS_PER_THREAD; ++j) {
        int p = gtid + j * T;
        if (p < npairs) {
            P[j] = __builtin_nontemporal_load(&yp2[p]);
            Y[j] = __builtin_nontemporal_load(&yt2[p]);
        }
    }

    // Phase 2: compute + store per pair.
#pragma unroll
    for (int j = 0; j < PAIRS_PER_THREAD; ++j) {
        int p = gtid + j * T;
        if (p >= npairs) continue;

        float L0, g00, g01, h000, h001, h011;
        float L1, g10, g11, h100, h101, h111;
        nll_elem(P[j].x, P[j].y, Y[j].x, L0, g00, g01, h000, h001, h011);
        nll_elem(P[j].z, P[j].w, Y[j].y, L1, g10, g11, h100, h101, h111);

        v2f Lv; Lv.x = L0; Lv.y = L1;
        v4f gv; gv.x = g00; gv.y = g01; gv.z = g10; gv.w = g11;
        v4f h0v; h0v.x = h000; h0v.y = h001; h0v.z = h001; h0v.w = h011;
        v4f h1v; h1v.x = h100; h1v.y = h101; h1v.z = h101; h1v.w = h111;

        __builtin_nontemporal_store(Lv,  &loss2[p]);
        __builtin_nontemporal_store(gv,  &g2[p]);
        __builtin_nontemporal_store(h0v, &h1[2 * p]);
        __builtin_nontemporal_store(h1v, &h1[2 * p + 1]);
    }
}

// Scalar tail for odd N (not hit at N=2^23, kept for correctness).
__global__ void unll_tail(const float* __restrict__ yp, const float* __restrict__ yt,
                          float* __restrict__ out_loss, float* __restrict__ out_g,
                          float* __restrict__ out_h, int i)
{
    float L, g0, g1, h00, h01, h11;
    nll_elem(yp[2 * i], yp[2 * i + 1], yt[i], L, g0, g1, h00, h01, h11);
    out_loss[i] = L;
    out_g[2 * i] = g0; out_g[2 * i + 1] = g1;
    out_h[4 * i] = h00; out_h[4 * i + 1] = h01;
    out_h[4 * i + 2] = h01; out_h[4 * i + 3] = h11;
}

extern "C" void kernel_launch(void* const* d_in, const int* in_sizes, int n_in,
                              void* d_out, int out_size, void* d_ws, size_t ws_size,
                              hipStream_t stream) {
    const float* y_pred = (const float*)d_in[0];  // [N,2]
    const float* y_true = (const float*)d_in[1];  // [N]
    float* out = (float*)d_out;                   // loss[N] | d[2N] | dd[4N]

    const int N = in_sizes[1];
    const int NP = N / 2;

    float* out_loss = out;
    float* out_g    = out + (size_t)N;
    float* out_h    = out + (size_t)3 * N;

    const int block = 256;
    const int elems_per_block = block * PAIRS_PER_THREAD;
    int grid = (NP + elems_per_block - 1) / elems_per_block;  // 4096 @ N=2^23

    // DOUBLE LAUNCH (idempotent) — diagnostic amplification: dur = fixed + 2k.
    for (int rep = 0; rep < 2; ++rep) {
        unll_kernel<<<grid, block, 0, stream>>>(
            (const v4f*)y_pred, (const v2f*)y_true,
            (v2f*)out_loss, (v4f*)out_g, (v4f*)out_h, NP);
    }

    if (N & 1) {
        unll_tail<<<1, 1, 0, stream>>>(y_pred, y_true, out_loss, out_g, out_h, N - 1);
    }
}

// Round 6
// 288.661 us; speedup vs baseline: 1.3957x; 1.3957x over previous
//
#include <hip/hip_runtime.h>
#include <math.h>

// Gaussian NLL + analytic grad + Hessian wrt (mu, pre-softplus-std).
// Streaming: 100.7 MB in, 234.9 MB out = 335.5 MB @ N=2^23.
//
// Session findings (R2-R5, double-launch decomposition):
//   - timed dur = fixed harness cost ~233 us (incl. ~145 us poison fill
//     @6.5 TB/s) + kernel k. Kernel k ~= 73 us (4.6 TB/s effective).
//   - per-thread batching trend is MONOTONE BAD: 1 elem/thread one-shot
//     (294.8) < grid-stride x16 (299.6) < 2-elem pairs (306.4) << 8-elem
//     batched (k=85, 402.9 doubled). TLP >> ILP for streaming on MI355X.
//   - nt hints, transaction width, MLP batching: all null or negative.
// This round: revert to the measured-best shape — 1 element per thread,
// one-shot grid, nt hints, single launch.

__global__ __launch_bounds__(256) void unll_kernel(
    const float* __restrict__ yp,  // [N,2] of (mu, s)
    const float* __restrict__ yt,  // [N]
    float* __restrict__ out_loss,  // [N]
    float* __restrict__ out_g,     // [N,2] of (g_mu, g_s)
    float* __restrict__ out_h,     // [N,2,2] of (h00,h01,h10,h11)
    int n)
{
    int i = blockIdx.x * blockDim.x + threadIdx.x;
    if (i >= n) return;

    typedef float v2f __attribute__((ext_vector_type(2)));
    typedef float v4f __attribute__((ext_vector_type(4)));

    v2f   p = __builtin_nontemporal_load((const v2f*)(yp + 2 * (size_t)i));
    float y = __builtin_nontemporal_load(yt + i);

    float mu = p.x;
    float s  = p.y;

    // stable softplus: max(s,0) + log1p(exp(-|s|))
    float e    = __expf(-fabsf(s));
    float rec  = 1.0f / (1.0f + e);           // sigmoid(|s|)
    float sig  = (s >= 0.0f) ? rec : e * rec; // sigmoid(s), reuses e
    float stdv = fmaxf(s, 0.0f) + __logf(1.0f + e);
    float inv  = 1.0f / stdv;
    float z    = (y - mu) * inv;
    float z2   = z * z;

    float L  = 0.5f * z2 + __logf(stdv) + 0.91893853320467274178f; // +0.5*log(2pi)
    float g0 = -z * inv;
    float g1 = sig * (1.0f - z2) * inv;

    float inv2 = inv * inv;
    float h00 = inv2;
    float h01 = 2.0f * z * sig * inv2;
    float h11 = sig * (1.0f - sig) * (1.0f - z2) * inv
              + sig * sig * (3.0f * z2 - 1.0f) * inv2;

    v2f g; g.x = g0; g.y = g1;
    v4f h; h.x = h00; h.y = h01; h.z = h01; h.w = h11;

    __builtin_nontemporal_store(L, out_loss + i);
    __builtin_nontemporal_store(g, (v2f*)(out_g + 2 * (size_t)i));
    __builtin_nontemporal_store(h, (v4f*)(out_h + 4 * (size_t)i));
}

extern "C" void kernel_launch(void* const* d_in, const int* in_sizes, int n_in,
                              void* d_out, int out_size, void* d_ws, size_t ws_size,
                              hipStream_t stream) {
    const float* y_pred = (const float*)d_in[0];  // [N,2]
    const float* y_true = (const float*)d_in[1];  // [N]
    float* out = (float*)d_out;                   // loss[N] | d[2N] | dd[4N]

    const int N = in_sizes[1];

    float* out_loss = out;
    float* out_g    = out + (size_t)N;
    float* out_h    = out + (size_t)3 * N;

    const int block = 256;
    const int grid = (N + block - 1) / block;   // one-shot: max TLP
    unll_kernel<<<grid, block, 0, stream>>>(
        y_pred, y_true, out_loss, out_g, out_h, N);
}